// Round 15
// baseline (239.664 us; speedup 1.0000x reference)
//
#include <hip/hip_runtime.h>
#include <hip/hip_bf16.h>

#define B_  8
#define S_  512
#define D_  1024
#define H_  16
#define DK_ 64
#define TB_ 64
#define SCALE_ 0.125f      // DK^-0.5

typedef __attribute__((ext_vector_type(8))) short          bh8;    // 8 bf16 MFMA frag
typedef __attribute__((ext_vector_type(4))) float          f32x4;  // MFMA acc
typedef __attribute__((ext_vector_type(8))) unsigned short us8;    // 16B bf16 store

__device__ __forceinline__ unsigned short f2bf(float f) {
    unsigned u = __float_as_uint(f);
    unsigned r = 0x7fffu + ((u >> 16) & 1u);
    return (unsigned short)((u + r) >> 16);
}
__device__ __forceinline__ float bf2f(unsigned short u) {
    return __uint_as_float((unsigned)u << 16);
}

// async global->LDS DMA, 16B per lane; LDS dest = wave-uniform base + lane*16
__device__ __forceinline__ void gl16(const unsigned short* g, unsigned short* l) {
    __builtin_amdgcn_global_load_lds(
        (const __attribute__((address_space(1))) void*)g,
        (__attribute__((address_space(3))) void*)l, 16, 0, 0);
}

// ---------------------------------------------------------------------------
// Fused prep kernel (one launch, 5120 blocks):
//   [0,2048)    : x fp32 -> bf16 flat convert
//   [2048,3072) : 4x weight transpose+convert (256 blocks each)
//   [3072,5120) : temporal-bias MLP -> bf16, padding mask folded (-1e30)
// ---------------------------------------------------------------------------
__global__ __launch_bounds__(256)
void prep_kernel(const float* __restrict__ x, unsigned short* __restrict__ xb,
                 const float* __restrict__ w0, const float* __restrict__ w1w,
                 const float* __restrict__ w2w, const float* __restrict__ w3w,
                 unsigned short* __restrict__ o0, unsigned short* __restrict__ o1,
                 unsigned short* __restrict__ o2, unsigned short* __restrict__ o3,
                 const float* __restrict__ tm, const int* __restrict__ pmask,
                 const float* __restrict__ tw1, const float* __restrict__ tb1,
                 const float* __restrict__ tw2, const float* __restrict__ tb2,
                 unsigned short* __restrict__ biasb)
{
    __shared__ float smem[64 * 65];
    const int bid = blockIdx.x;
    const int tid = threadIdx.x;

    if (bid < 2048) {
        // ---- cvt_x ----
        int i = bid * 256 + tid;
        float4 a = *(const float4*)&x[(size_t)i * 8];
        float4 b = *(const float4*)&x[(size_t)i * 8 + 4];
        us8 o;
        o[0] = f2bf(a.x); o[1] = f2bf(a.y); o[2] = f2bf(a.z); o[3] = f2bf(a.w);
        o[4] = f2bf(b.x); o[5] = f2bf(b.y); o[6] = f2bf(b.z); o[7] = f2bf(b.w);
        *(us8*)&xb[(size_t)i * 8] = o;
    } else if (bid < 3072) {
        // ---- cvt_wt (4 weights x 256 blocks of 64x64) ----
        int idx = bid - 2048;
        int z = idx >> 8, local = idx & 255;
        int bx = local & 15, by = local >> 4;
        const float* W = (z == 0) ? w0 : (z == 1) ? w1w : (z == 2) ? w2w : w3w;
        unsigned short* Wt = (z == 0) ? o0 : (z == 1) ? o1 : (z == 2) ? o2 : o3;
        float (*t)[65] = (float(*)[65])smem;
        const int c  = tid & 63;
        const int r0 = tid >> 6;
        #pragma unroll
        for (int i = 0; i < 16; ++i) {
            int r = r0 + i * 4;
            t[r][c] = W[(size_t)(by * 64 + r) * 1024 + bx * 64 + c];
        }
        __syncthreads();
        #pragma unroll
        for (int i = 0; i < 16; ++i) {
            int r = r0 + i * 4;
            Wt[(size_t)(bx * 64 + r) * 1024 + by * 64 + c] = f2bf(t[c][r]);
        }
    } else {
        // ---- tbias ----
        float* sw1 = smem;
        float* sb1 = smem + 64;
        float* sw2 = smem + 128;
        if (tid < TB_) {
            sw1[tid] = tw1[tid];
            sb1[tid] = tb1[tid];
            sw2[tid] = tw2[tid];
        }
        __syncthreads();
        const float ec  = 2.7182818284590452f;
        const float b2v = tb2[0];
        const int n = B_ * S_ * S_;
        for (int i = (bid - 3072) * 256 + tid; i < n; i += 2048 * 256) {
            int bb = i >> 18;
            int jj = i & (S_ - 1);
            float t   = 1.0f / logf(ec + tm[i]);
            float acc = b2v;
            #pragma unroll
            for (int j = 0; j < TB_; ++j) {
                float h = fmaf(t, sw1[j], sb1[j]);
                h = (h >= 0.f) ? h : 0.2f * h;
                acc = fmaf(h, sw2[j], acc);
            }
            biasb[i] = f2bf((pmask[bb * S_ + jj] == 0) ? -1e30f : acc);
        }
    }
}

// ---------------------------------------------------------------------------
// Fused QKV GEMM (R7-proven best: 44.5us, 0 conflicts): BM=128, BN=64, BK=64,
// 4 waves (2x2), wave tile 64x32. global_load_lds into LINEAR LDS with
// both-sides XOR swizzle. Grid (32,48) = 1536 blocks = 6/CU (LDS 24KB).
// Q,K -> (B,H,S,DK); V -> (B,H,DK,S).
// ---------------------------------------------------------------------------
__global__ __launch_bounds__(256)
void gemm_qkv_kernel(const unsigned short* __restrict__ A,
                     const unsigned short* __restrict__ Wt,   // 3072x1024
                     const float* __restrict__ bq, const float* __restrict__ bk,
                     const float* __restrict__ bv,
                     unsigned short* __restrict__ qo,
                     unsigned short* __restrict__ ko,
                     unsigned short* __restrict__ vo)
{
    __shared__ unsigned short As[128 * 64];
    __shared__ unsigned short Bs[64 * 64];
    const int tid  = threadIdx.x;
    const int lane = tid & 63;
    const int wid  = tid >> 6;
    const int wr   = wid >> 1, wc = wid & 1;
    const int row0 = blockIdx.x * 128;
    const int col0 = blockIdx.y * 64;

    f32x4 acc[4][2] = {};

    const int fr = lane & 15;
    const int g  = lane >> 4;
    const int sr = lane >> 3;                    // staging row within 8-row issue
    const int sc = ((lane & 7) ^ sr) * 8;        // pre-swizzled global col (elements)

    for (int k0 = 0; k0 < 1024; k0 += 64) {
        #pragma unroll
        for (int i = 0; i < 4; ++i)
            gl16(&A [(size_t)(row0 + wid * 32 + i * 8 + sr) * 1024 + k0 + sc],
                 &As[(wid * 32 + i * 8) * 64]);
        #pragma unroll
        for (int i = 0; i < 2; ++i)
            gl16(&Wt[(size_t)(col0 + wid * 16 + i * 8 + sr) * 1024 + k0 + sc],
                 &Bs[(wid * 16 + i * 8) * 64]);
        __syncthreads();    // vmcnt(0) drain: DMA landed
        #pragma unroll
        for (int ks = 0; ks < 2; ++ks) {
            const int ch = (ks * 4 + g) ^ (fr & 7);   // swizzled chunk for this lane
            bh8 af[4], bfr[2];
            #pragma unroll
            for (int r = 0; r < 4; ++r)
                af[r]  = *(const bh8*)&As[(wr * 64 + r * 16 + fr) * 64 + ch * 8];
            #pragma unroll
            for (int c = 0; c < 2; ++c)
                bfr[c] = *(const bh8*)&Bs[(wc * 32 + c * 16 + fr) * 64 + ch * 8];
            #pragma unroll
            for (int r = 0; r < 4; ++r)
                #pragma unroll
                for (int c = 0; c < 2; ++c)
                    acc[r][c] = __builtin_amdgcn_mfma_f32_16x16x32_bf16(
                        af[r], bfr[c], acc[r][c], 0, 0, 0);
        }
        __syncthreads();    // frag reads done before next DMA overwrites
    }

    const int nh = col0 >> 10;                 // 0=Q 1=K 2=V (block-uniform)
    const float* bsel = (nh == 0) ? bq : (nh == 1) ? bk : bv;
    unsigned short* outp = (nh == 0) ? qo : (nh == 1) ? ko : vo;

    #pragma unroll
    for (int r = 0; r < 4; ++r) {
        #pragma unroll
        for (int c = 0; c < 2; ++c) {
            int n  = col0 + wc * 32 + c * 16 + fr;
            int nn = n & 1023;
            float bn = bsel[nn];
            int hh = nn >> 6, dd = nn & 63;
            #pragma unroll
            for (int j = 0; j < 4; ++j) {
                int m = row0 + wr * 64 + r * 16 + g * 4 + j;
                float o = acc[r][c][j] + bn;
                int bb = m >> 9, ss = m & 511;
                if (nh == 2)
                    outp[((size_t)((bb * H_ + hh) * DK_ + dd)) * S_ + ss] = f2bf(o);
                else
                    outp[((size_t)((bb * H_ + hh) * S_ + ss)) * DK_ + dd] = f2bf(o);
            }
        }
    }
}

// ===========================================================================
// Proj GEMM (R11-proven dbuf): 2-phase double-buffered 64x64 tile, BK=64,
// 4 waves, wave 32x32. Grid (64,16) = 1024 blocks = 4/CU.
// ===========================================================================
#define GEMM_STAGE(buf, k0) do {                                         \
    gl16(Arow + (k0),            &As[buf][(w * 16    ) * 64]);           \
    gl16(Arow + (k0) + 8 * 1024, &As[buf][(w * 16 + 8) * 64]);           \
    gl16(Brow + (k0),            &Bs[buf][(w * 16    ) * 64]);           \
    gl16(Brow + (k0) + 8 * 1024, &Bs[buf][(w * 16 + 8) * 64]);           \
} while (0)

#define GEMM_COMPUTE(buf) do {                                           \
    _Pragma("unroll")                                                    \
    for (int ks = 0; ks < 2; ++ks) {                                     \
        const int ch = (ks * 4 + g) ^ (fr & 7);                          \
        bh8 af[2], bf[2];                                                \
        _Pragma("unroll")                                                \
        for (int r = 0; r < 2; ++r)                                      \
            af[r] = *(const bh8*)&As[buf][(wr * 32 + r * 16 + fr) * 64 + ch * 8]; \
        _Pragma("unroll")                                                \
        for (int c = 0; c < 2; ++c)                                      \
            bf[c] = *(const bh8*)&Bs[buf][(wc * 32 + c * 16 + fr) * 64 + ch * 8]; \
        _Pragma("unroll")                                                \
        for (int r = 0; r < 2; ++r)                                      \
            _Pragma("unroll")                                            \
            for (int c = 0; c < 2; ++c)                                  \
                acc[r][c] = __builtin_amdgcn_mfma_f32_16x16x32_bf16(     \
                    af[r], bf[c], acc[r][c], 0, 0, 0);                   \
    }                                                                    \
} while (0)

__global__ __launch_bounds__(256)
void gemm_proj_kernel(const unsigned short* __restrict__ A,
                      const unsigned short* __restrict__ Wt,
                      const float* __restrict__ bias,
                      float* __restrict__ C)
{
    __shared__ unsigned short As[2][64 * 64];
    __shared__ unsigned short Bs[2][64 * 64];
    const int tid  = threadIdx.x;
    const int lane = tid & 63;
    const int w    = tid >> 6;
    const int wr   = w >> 1, wc = w & 1;
    const int row0 = blockIdx.x * 64;
    const int col0 = blockIdx.y * 64;

    f32x4 acc[2][2] = {};
    const int fr = lane & 15;
    const int g  = lane >> 4;
    const int sr = lane >> 3;
    const int sc = ((lane & 7) ^ sr) * 8;

    const unsigned short* Arow = A  + (size_t)(row0 + w * 16 + sr) * 1024 + sc;
    const unsigned short* Brow = Wt + (size_t)(col0 + w * 16 + sr) * 1024 + sc;

    GEMM_STAGE(0, 0);
    __syncthreads();
    int cur = 0;
    #pragma unroll 1
    for (int t = 0; t < 15; ++t) {
        GEMM_STAGE(cur ^ 1, (t + 1) * 64);
        GEMM_COMPUTE(cur);
        __syncthreads();
        cur ^= 1;
    }
    GEMM_COMPUTE(cur);

    #pragma unroll
    for (int r = 0; r < 2; ++r) {
        #pragma unroll
        for (int c = 0; c < 2; ++c) {
            int n = col0 + wc * 32 + c * 16 + fr;
            float bn = bias[n];
            #pragma unroll
            for (int j = 0; j < 4; ++j) {
                int m = row0 + wr * 32 + r * 16 + g * 4 + j;
                C[(size_t)m * 1024 + n] = acc[r][c][j] + bn;
            }
        }
    }
}

// ---------------------------------------------------------------------------
// MFMA flash attention (R11-proven direct staging; bf16 bias). 1D grid 1024,
// XCD swizzle (one batch/XCD). 4 waves, QBLK=64, KV tile 64. Q frags in regs;
// K/Vt/P in LDS stride 72. P band wave-private (lgkmcnt only, no barrier).
// ---------------------------------------------------------------------------
__global__ __launch_bounds__(256)
void attn_kernel(const unsigned short* __restrict__ q,
                 const unsigned short* __restrict__ k,
                 const unsigned short* __restrict__ vt,
                 const unsigned short* __restrict__ biasm,
                 unsigned short* __restrict__ outb)
{
    __shared__ unsigned short Kl[64][72];
    __shared__ unsigned short Vl[64][72];
    __shared__ unsigned short Pl[64][72];

    const int tid  = threadIdx.x;
    const int lane = tid & 63;
    const int w    = tid >> 6;
    const int lin = (blockIdx.x & 7) * 128 + (blockIdx.x >> 3);
    const int h   = lin & 15;
    const int qt  = (lin >> 4) & 7;
    const int b   = lin >> 7;
    const int q0  = qt * 64;

    const int l15 = lane & 15;
    const int g   = lane >> 4;

    const size_t hb  = (size_t)(b * H_ + h) * S_;
    const unsigned short* kbase  = k  + hb * DK_;
    const unsigned short* vtbase = vt + ((size_t)(b * H_ + h) * DK_) * S_;

    const int qrow_a = q0 + w * 16 + l15;
    bh8 aq0 = *(const bh8*)&q[(hb + qrow_a) * DK_ +      g * 8];
    bh8 aq1 = *(const bh8*)&q[(hb + qrow_a) * DK_ + 32 + g * 8];

    const int qd = q0 + w * 16 + g * 4;

    f32x4 acc_o[4] = {};
    float m_run[4] = { -1e30f, -1e30f, -1e30f, -1e30f };
    float l_run[4] = {};

    for (int kt = 0; kt <= qt; ++kt) {
        __syncthreads();
        #pragma unroll
        for (int s = 0; s < 2; ++s) {
            int u  = tid + s * 256;
            int r  = u >> 3;
            int c8 = (u & 7) * 8;
            *(int4*)&Kl[r][c8] = *(const int4*)&kbase [(size_t)(kt * 64 + r) * DK_ + c8];
            *(int4*)&Vl[r][c8] = *(const int4*)&vtbase[(size_t)r * S_ + kt * 64 + c8];
        }
        __syncthreads();

        f32x4 sc[4];
        #pragma unroll
        for (int c = 0; c < 4; ++c) {
            bh8 bk0 = *(const bh8*)&Kl[c * 16 + l15][     g * 8];
            bh8 bk1 = *(const bh8*)&Kl[c * 16 + l15][32 + g * 8];
            f32x4 z = {};
            z = __builtin_amdgcn_mfma_f32_16x16x32_bf16(aq0, bk0, z, 0, 0, 0);
            sc[c] = __builtin_amdgcn_mfma_f32_16x16x32_bf16(aq1, bk1, z, 0, 0, 0);
        }

        float sv[4][4];
        #pragma unroll
        for (int j = 0; j < 4; ++j) {
            const unsigned short* br = biasm + ((size_t)b * S_ + qd + j) * S_ + kt * 64;
            #pragma unroll
            for (int c = 0; c < 4; ++c)
                sv[c][j] = fmaf(sc[c][j], SCALE_, bf2f(br[c * 16 + l15]));
        }
        if (kt == qt) {
            #pragma unroll
            for (int c = 0; c < 4; ++c) {
                int kloc = c * 16 + l15;
                #pragma unroll
                for (int j = 0; j < 4; ++j)
                    if (kloc > w * 16 + g * 4 + j) sv[c][j] = -1e30f;
            }
        }

        #pragma unroll
        for (int j = 0; j < 4; ++j) {
            float mt = fmaxf(fmaxf(sv[0][j], sv[1][j]), fmaxf(sv[2][j], sv[3][j]));
            mt = fmaxf(mt, __shfl_xor(mt, 1));
            mt = fmaxf(mt, __shfl_xor(mt, 2));
            mt = fmaxf(mt, __shfl_xor(mt, 4));
            mt = fmaxf(mt, __shfl_xor(mt, 8));
            float m_new = fmaxf(m_run[j], mt);
            float resc  = __expf(m_run[j] - m_new);
            float psum  = 0.f;
            #pragma unroll
            for (int c = 0; c < 4; ++c) {
                float p = __expf(sv[c][j] - m_new);
                Pl[w * 16 + g * 4 + j][c * 16 + l15] = f2bf(p);
                psum += p;
            }
            psum += __shfl_xor(psum, 1);
            psum += __shfl_xor(psum, 2);
            psum += __shfl_xor(psum, 4);
            psum += __shfl_xor(psum, 8);
            l_run[j] = l_run[j] * resc + psum;
            m_run[j] = m_new;
            acc_o[0][j] *= resc; acc_o[1][j] *= resc;
            acc_o[2][j] *= resc; acc_o[3][j] *= resc;
        }

        asm volatile("s_waitcnt lgkmcnt(0)" ::: "memory");

        bh8 ap0 = *(const bh8*)&Pl[w * 16 + l15][     g * 8];
        bh8 ap1 = *(const bh8*)&Pl[w * 16 + l15][32 + g * 8];
        #pragma unroll
        for (int c2 = 0; c2 < 4; ++c2) {
            bh8 bv0 = *(const bh8*)&Vl[c2 * 16 + l15][     g * 8];
            bh8 bv1 = *(const bh8*)&Vl[c2 * 16 + l15][32 + g * 8];
            acc_o[c2] = __builtin_amdgcn_mfma_f32_16x16x32_bf16(ap0, bv0, acc_o[c2], 0, 0, 0);
            acc_o[c2] = __builtin_amdgcn_mfma_f32_16x16x32_bf16(ap1, bv1, acc_o[c2], 0, 0, 0);
        }
    }

    #pragma unroll
    for (int j = 0; j < 4; ++j) {
        float linv = 1.f / l_run[j];
        #pragma unroll
        for (int c2 = 0; c2 < 4; ++c2)
            outb[((size_t)(b * S_ + qd + j)) * D_ + h * DK_ + c2 * 16 + l15] =
                f2bf(acc_o[c2][j] * linv);
    }
}

extern "C" void kernel_launch(void* const* d_in, const int* in_sizes, int n_in,
                              void* d_out, int out_size, void* d_ws, size_t ws_size,
                              hipStream_t stream)
{
    const float* x     = (const float*)d_in[0];
    const int*   pm    = (const int*)  d_in[1];
    const float* tm    = (const float*)d_in[2];
    const float* wq    = (const float*)d_in[3];
    const float* bq    = (const float*)d_in[4];
    const float* wk    = (const float*)d_in[5];
    const float* bk    = (const float*)d_in[6];
    const float* wv    = (const float*)d_in[7];
    const float* bv    = (const float*)d_in[8];
    const float* wp    = (const float*)d_in[9];
    const float* bp    = (const float*)d_in[10];
    const float* w_tb1 = (const float*)d_in[11];
    const float* b_tb1 = (const float*)d_in[12];
    const float* w_tb2 = (const float*)d_in[13];
    const float* b_tb2 = (const float*)d_in[14];

    char* wsb = (char*)d_ws;
    const size_t MB = 1u << 20;
    unsigned short* xb   = (unsigned short*)wsb;              // 8MB; reused as attn out
    unsigned short* wqkv = (unsigned short*)(wsb + 8  * MB);  // 6MB (3072x1024 bf16)
    unsigned short* wtp  = (unsigned short*)(wsb + 14 * MB);  // 2MB
    unsigned short* qw   = (unsigned short*)(wsb + 16 * MB);  // 8MB (B,H,S,DK)
    unsigned short* kw   = (unsigned short*)(wsb + 24 * MB);  // 8MB (B,H,S,DK)
    unsigned short* vtw  = (unsigned short*)(wsb + 32 * MB);  // 8MB (B,H,DK,S)
    unsigned short* bw   = (unsigned short*)(wsb + 40 * MB);  // 4MB bf16 (B,S,S)

    prep_kernel<<<5120, 256, 0, stream>>>(
        x, xb, wq, wk, wv, wp,
        wqkv, wqkv + 1048576, wqkv + 2097152, wtp,
        tm, pm, w_tb1, b_tb1, w_tb2, b_tb2, bw);

    dim3 gqkv(32, 48);
    gemm_qkv_kernel<<<gqkv, 256, 0, stream>>>(xb, wqkv, bq, bk, bv, qw, kw, vtw);

    attn_kernel<<<1024, 256, 0, stream>>>(qw, kw, vtw, bw, xb /*out*/);

    dim3 gp(64, 16);
    gemm_proj_kernel<<<gp, 256, 0, stream>>>(xb, wtp, bp, (float*)d_out);
}

// Round 16
// 211.331 us; speedup vs baseline: 1.1341x; 1.1341x over previous
//
#include <hip/hip_runtime.h>
#include <hip/hip_bf16.h>

#define B_  8
#define S_  512
#define D_  1024
#define H_  16
#define DK_ 64
#define TB_ 64
#define SCALE_ 0.125f      // DK^-0.5

typedef __attribute__((ext_vector_type(8))) short          bh8;    // 8 bf16 MFMA frag
typedef __attribute__((ext_vector_type(4))) float          f32x4;  // MFMA acc
typedef __attribute__((ext_vector_type(8))) unsigned short us8;    // 16B bf16 store

__device__ __forceinline__ unsigned short f2bf(float f) {
    unsigned u = __float_as_uint(f);
    unsigned r = 0x7fffu + ((u >> 16) & 1u);
    return (unsigned short)((u + r) >> 16);
}
__device__ __forceinline__ float bf2f(unsigned short u) {
    return __uint_as_float((unsigned)u << 16);
}

// async global->LDS DMA, 16B per lane; LDS dest = wave-uniform base + lane*16
__device__ __forceinline__ void gl16(const unsigned short* g, unsigned short* l) {
    __builtin_amdgcn_global_load_lds(
        (const __attribute__((address_space(1))) void*)g,
        (__attribute__((address_space(3))) void*)l, 16, 0, 0);
}

// ---------------------------------------------------------------------------
// fp32 -> bf16 flat convert (x: 4M elements)
// ---------------------------------------------------------------------------
__global__ __launch_bounds__(256)
void cvt_x_kernel(const float* __restrict__ in, unsigned short* __restrict__ out, int n8)
{
    int i = blockIdx.x * 256 + threadIdx.x;
    if (i >= n8) return;
    float4 a = *(const float4*)&in[(size_t)i * 8];
    float4 b = *(const float4*)&in[(size_t)i * 8 + 4];
    us8 o;
    o[0] = f2bf(a.x); o[1] = f2bf(a.y); o[2] = f2bf(a.z); o[3] = f2bf(a.w);
    o[4] = f2bf(b.x); o[5] = f2bf(b.y); o[6] = f2bf(b.z); o[7] = f2bf(b.w);
    *(us8*)&out[(size_t)i * 8] = o;
}

// ---------------------------------------------------------------------------
// Weight transpose+convert, 4 weights in one launch (z selects):
// Wt[n][k] = bf16(W[k][n])   (1024x1024 each)
// ---------------------------------------------------------------------------
__global__ __launch_bounds__(256)
void cvt_wt4_kernel(const float* __restrict__ w0, const float* __restrict__ w1,
                    const float* __restrict__ w2, const float* __restrict__ w3,
                    unsigned short* __restrict__ o0, unsigned short* __restrict__ o1,
                    unsigned short* __restrict__ o2, unsigned short* __restrict__ o3)
{
    __shared__ float t[64][65];
    const int z = blockIdx.z;
    const float* W = (z == 0) ? w0 : (z == 1) ? w1 : (z == 2) ? w2 : w3;
    unsigned short* Wt = (z == 0) ? o0 : (z == 1) ? o1 : (z == 2) ? o2 : o3;
    const int bx = blockIdx.x, by = blockIdx.y;
    const int c  = threadIdx.x & 63;
    const int r0 = threadIdx.x >> 6;
    #pragma unroll
    for (int i = 0; i < 16; ++i) {
        int r = r0 + i * 4;
        t[r][c] = W[(size_t)(by * 64 + r) * 1024 + bx * 64 + c];
    }
    __syncthreads();
    #pragma unroll
    for (int i = 0; i < 16; ++i) {
        int r = r0 + i * 4;
        Wt[(size_t)(bx * 64 + r) * 1024 + by * 64 + c] = f2bf(t[c][r]);
    }
}

// ---------------------------------------------------------------------------
// Temporal bias MLP -> bf16 output, padding mask folded in (-1e30 masked)
// ---------------------------------------------------------------------------
__global__ __launch_bounds__(256)
void tbias_kernel(const float* __restrict__ tm, const int* __restrict__ pmask,
                  const float* __restrict__ w1, const float* __restrict__ b1,
                  const float* __restrict__ w2, const float* __restrict__ b2,
                  unsigned short* __restrict__ bias)
{
    __shared__ float sw1[TB_], sb1[TB_], sw2[TB_];
    if (threadIdx.x < TB_) {
        sw1[threadIdx.x] = w1[threadIdx.x];
        sb1[threadIdx.x] = b1[threadIdx.x];
        sw2[threadIdx.x] = w2[threadIdx.x];
    }
    __syncthreads();
    const float ec  = 2.7182818284590452f;
    const float b2v = b2[0];
    const int n = B_ * S_ * S_;
    for (int i = blockIdx.x * blockDim.x + threadIdx.x; i < n;
         i += gridDim.x * blockDim.x) {
        int bb = i >> 18;
        int jj = i & (S_ - 1);
        float t   = 1.0f / logf(ec + tm[i]);
        float acc = b2v;
        #pragma unroll
        for (int j = 0; j < TB_; ++j) {
            float h = fmaf(t, sw1[j], sb1[j]);
            h = (h >= 0.f) ? h : 0.2f * h;
            acc = fmaf(h, sw2[j], acc);
        }
        bias[i] = f2bf((pmask[bb * S_ + jj] == 0) ? -1e30f : acc);
    }
}

// ---------------------------------------------------------------------------
// Fused QKV GEMM (R7-proven best: 44.5us, 0 conflicts): BM=128, BN=64, BK=64,
// 4 waves (2x2), wave tile 64x32. global_load_lds into LINEAR LDS with
// both-sides XOR swizzle. Grid (32,48) = 1536 blocks = 6/CU (LDS 24KB).
// Q,K -> (B,H,S,DK); V -> (B,H,DK,S).
// ---------------------------------------------------------------------------
__global__ __launch_bounds__(256)
void gemm_qkv_kernel(const unsigned short* __restrict__ A,
                     const unsigned short* __restrict__ Wt,   // 3072x1024
                     const float* __restrict__ bq, const float* __restrict__ bk,
                     const float* __restrict__ bv,
                     unsigned short* __restrict__ qo,
                     unsigned short* __restrict__ ko,
                     unsigned short* __restrict__ vo)
{
    __shared__ unsigned short As[128 * 64];
    __shared__ unsigned short Bs[64 * 64];
    const int tid  = threadIdx.x;
    const int lane = tid & 63;
    const int wid  = tid >> 6;
    const int wr   = wid >> 1, wc = wid & 1;
    const int row0 = blockIdx.x * 128;
    const int col0 = blockIdx.y * 64;

    f32x4 acc[4][2] = {};

    const int fr = lane & 15;
    const int g  = lane >> 4;
    const int sr = lane >> 3;                    // staging row within 8-row issue
    const int sc = ((lane & 7) ^ sr) * 8;        // pre-swizzled global col (elements)

    for (int k0 = 0; k0 < 1024; k0 += 64) {
        #pragma unroll
        for (int i = 0; i < 4; ++i)
            gl16(&A [(size_t)(row0 + wid * 32 + i * 8 + sr) * 1024 + k0 + sc],
                 &As[(wid * 32 + i * 8) * 64]);
        #pragma unroll
        for (int i = 0; i < 2; ++i)
            gl16(&Wt[(size_t)(col0 + wid * 16 + i * 8 + sr) * 1024 + k0 + sc],
                 &Bs[(wid * 16 + i * 8) * 64]);
        __syncthreads();    // vmcnt(0) drain: DMA landed
        #pragma unroll
        for (int ks = 0; ks < 2; ++ks) {
            const int ch = (ks * 4 + g) ^ (fr & 7);   // swizzled chunk for this lane
            bh8 af[4], bfr[2];
            #pragma unroll
            for (int r = 0; r < 4; ++r)
                af[r]  = *(const bh8*)&As[(wr * 64 + r * 16 + fr) * 64 + ch * 8];
            #pragma unroll
            for (int c = 0; c < 2; ++c)
                bfr[c] = *(const bh8*)&Bs[(wc * 32 + c * 16 + fr) * 64 + ch * 8];
            #pragma unroll
            for (int r = 0; r < 4; ++r)
                #pragma unroll
                for (int c = 0; c < 2; ++c)
                    acc[r][c] = __builtin_amdgcn_mfma_f32_16x16x32_bf16(
                        af[r], bfr[c], acc[r][c], 0, 0, 0);
        }
        __syncthreads();    // frag reads done before next DMA overwrites
    }

    const int nh = col0 >> 10;                 // 0=Q 1=K 2=V (block-uniform)
    const float* bsel = (nh == 0) ? bq : (nh == 1) ? bk : bv;
    unsigned short* outp = (nh == 0) ? qo : (nh == 1) ? ko : vo;

    #pragma unroll
    for (int r = 0; r < 4; ++r) {
        #pragma unroll
        for (int c = 0; c < 2; ++c) {
            int n  = col0 + wc * 32 + c * 16 + fr;
            int nn = n & 1023;
            float bn = bsel[nn];
            int hh = nn >> 6, dd = nn & 63;
            #pragma unroll
            for (int j = 0; j < 4; ++j) {
                int m = row0 + wr * 64 + r * 16 + g * 4 + j;
                float o = acc[r][c][j] + bn;
                int bb = m >> 9, ss = m & 511;
                if (nh == 2)
                    outp[((size_t)((bb * H_ + hh) * DK_ + dd)) * S_ + ss] = f2bf(o);
                else
                    outp[((size_t)((bb * H_ + hh) * S_ + ss)) * DK_ + dd] = f2bf(o);
            }
        }
    }
}

// ===========================================================================
// Proj GEMM (R11-proven dbuf): 2-phase double-buffered 64x64 tile, BK=64,
// 4 waves, wave 32x32. Grid (64,16) = 1024 blocks = 4/CU.
// ===========================================================================
#define GEMM_STAGE(buf, k0) do {                                         \
    gl16(Arow + (k0),            &As[buf][(w * 16    ) * 64]);           \
    gl16(Arow + (k0) + 8 * 1024, &As[buf][(w * 16 + 8) * 64]);           \
    gl16(Brow + (k0),            &Bs[buf][(w * 16    ) * 64]);           \
    gl16(Brow + (k0) + 8 * 1024, &Bs[buf][(w * 16 + 8) * 64]);           \
} while (0)

#define GEMM_COMPUTE(buf) do {                                           \
    _Pragma("unroll")                                                    \
    for (int ks = 0; ks < 2; ++ks) {                                     \
        const int ch = (ks * 4 + g) ^ (fr & 7);                          \
        bh8 af[2], bf[2];                                                \
        _Pragma("unroll")                                                \
        for (int r = 0; r < 2; ++r)                                      \
            af[r] = *(const bh8*)&As[buf][(wr * 32 + r * 16 + fr) * 64 + ch * 8]; \
        _Pragma("unroll")                                                \
        for (int c = 0; c < 2; ++c)                                      \
            bf[c] = *(const bh8*)&Bs[buf][(wc * 32 + c * 16 + fr) * 64 + ch * 8]; \
        _Pragma("unroll")                                                \
        for (int r = 0; r < 2; ++r)                                      \
            _Pragma("unroll")                                            \
            for (int c = 0; c < 2; ++c)                                  \
                acc[r][c] = __builtin_amdgcn_mfma_f32_16x16x32_bf16(     \
                    af[r], bf[c], acc[r][c], 0, 0, 0);                   \
    }                                                                    \
} while (0)

__global__ __launch_bounds__(256)
void gemm_proj_kernel(const unsigned short* __restrict__ A,
                      const unsigned short* __restrict__ Wt,
                      const float* __restrict__ bias,
                      float* __restrict__ C)
{
    __shared__ unsigned short As[2][64 * 64];
    __shared__ unsigned short Bs[2][64 * 64];
    const int tid  = threadIdx.x;
    const int lane = tid & 63;
    const int w    = tid >> 6;
    const int wr   = w >> 1, wc = w & 1;
    const int row0 = blockIdx.x * 64;
    const int col0 = blockIdx.y * 64;

    f32x4 acc[2][2] = {};
    const int fr = lane & 15;
    const int g  = lane >> 4;
    const int sr = lane >> 3;
    const int sc = ((lane & 7) ^ sr) * 8;

    const unsigned short* Arow = A  + (size_t)(row0 + w * 16 + sr) * 1024 + sc;
    const unsigned short* Brow = Wt + (size_t)(col0 + w * 16 + sr) * 1024 + sc;

    GEMM_STAGE(0, 0);
    __syncthreads();
    int cur = 0;
    #pragma unroll 1
    for (int t = 0; t < 15; ++t) {
        GEMM_STAGE(cur ^ 1, (t + 1) * 64);
        GEMM_COMPUTE(cur);
        __syncthreads();
        cur ^= 1;
    }
    GEMM_COMPUTE(cur);

    #pragma unroll
    for (int r = 0; r < 2; ++r) {
        #pragma unroll
        for (int c = 0; c < 2; ++c) {
            int n = col0 + wc * 32 + c * 16 + fr;
            float bn = bias[n];
            #pragma unroll
            for (int j = 0; j < 4; ++j) {
                int m = row0 + wr * 32 + r * 16 + g * 4 + j;
                C[(size_t)m * 1024 + n] = acc[r][c][j] + bn;
            }
        }
    }
}

// ---------------------------------------------------------------------------
// MFMA flash attention (R11-proven direct staging; bf16 bias). 1D grid 1024,
// XCD swizzle (one batch/XCD). 4 waves, QBLK=64, KV tile 64. Q frags in regs;
// K/Vt/P in LDS stride 72. P band wave-private (lgkmcnt only, no barrier).
// ---------------------------------------------------------------------------
__global__ __launch_bounds__(256)
void attn_kernel(const unsigned short* __restrict__ q,
                 const unsigned short* __restrict__ k,
                 const unsigned short* __restrict__ vt,
                 const unsigned short* __restrict__ biasm,
                 unsigned short* __restrict__ outb)
{
    __shared__ unsigned short Kl[64][72];
    __shared__ unsigned short Vl[64][72];
    __shared__ unsigned short Pl[64][72];

    const int tid  = threadIdx.x;
    const int lane = tid & 63;
    const int w    = tid >> 6;
    const int lin = (blockIdx.x & 7) * 128 + (blockIdx.x >> 3);
    const int h   = lin & 15;
    const int qt  = (lin >> 4) & 7;
    const int b   = lin >> 7;
    const int q0  = qt * 64;

    const int l15 = lane & 15;
    const int g   = lane >> 4;

    const size_t hb  = (size_t)(b * H_ + h) * S_;
    const unsigned short* kbase  = k  + hb * DK_;
    const unsigned short* vtbase = vt + ((size_t)(b * H_ + h) * DK_) * S_;

    const int qrow_a = q0 + w * 16 + l15;
    bh8 aq0 = *(const bh8*)&q[(hb + qrow_a) * DK_ +      g * 8];
    bh8 aq1 = *(const bh8*)&q[(hb + qrow_a) * DK_ + 32 + g * 8];

    const int qd = q0 + w * 16 + g * 4;

    f32x4 acc_o[4] = {};
    float m_run[4] = { -1e30f, -1e30f, -1e30f, -1e30f };
    float l_run[4] = {};

    for (int kt = 0; kt <= qt; ++kt) {
        __syncthreads();
        #pragma unroll
        for (int s = 0; s < 2; ++s) {
            int u  = tid + s * 256;
            int r  = u >> 3;
            int c8 = (u & 7) * 8;
            *(int4*)&Kl[r][c8] = *(const int4*)&kbase [(size_t)(kt * 64 + r) * DK_ + c8];
            *(int4*)&Vl[r][c8] = *(const int4*)&vtbase[(size_t)r * S_ + kt * 64 + c8];
        }
        __syncthreads();

        f32x4 sc[4];
        #pragma unroll
        for (int c = 0; c < 4; ++c) {
            bh8 bk0 = *(const bh8*)&Kl[c * 16 + l15][     g * 8];
            bh8 bk1 = *(const bh8*)&Kl[c * 16 + l15][32 + g * 8];
            f32x4 z = {};
            z = __builtin_amdgcn_mfma_f32_16x16x32_bf16(aq0, bk0, z, 0, 0, 0);
            sc[c] = __builtin_amdgcn_mfma_f32_16x16x32_bf16(aq1, bk1, z, 0, 0, 0);
        }

        float sv[4][4];
        #pragma unroll
        for (int j = 0; j < 4; ++j) {
            const unsigned short* br = biasm + ((size_t)b * S_ + qd + j) * S_ + kt * 64;
            #pragma unroll
            for (int c = 0; c < 4; ++c)
                sv[c][j] = fmaf(sc[c][j], SCALE_, bf2f(br[c * 16 + l15]));
        }
        if (kt == qt) {
            #pragma unroll
            for (int c = 0; c < 4; ++c) {
                int kloc = c * 16 + l15;
                #pragma unroll
                for (int j = 0; j < 4; ++j)
                    if (kloc > w * 16 + g * 4 + j) sv[c][j] = -1e30f;
            }
        }

        #pragma unroll
        for (int j = 0; j < 4; ++j) {
            float mt = fmaxf(fmaxf(sv[0][j], sv[1][j]), fmaxf(sv[2][j], sv[3][j]));
            mt = fmaxf(mt, __shfl_xor(mt, 1));
            mt = fmaxf(mt, __shfl_xor(mt, 2));
            mt = fmaxf(mt, __shfl_xor(mt, 4));
            mt = fmaxf(mt, __shfl_xor(mt, 8));
            float m_new = fmaxf(m_run[j], mt);
            float resc  = __expf(m_run[j] - m_new);
            float psum  = 0.f;
            #pragma unroll
            for (int c = 0; c < 4; ++c) {
                float p = __expf(sv[c][j] - m_new);
                Pl[w * 16 + g * 4 + j][c * 16 + l15] = f2bf(p);
                psum += p;
            }
            psum += __shfl_xor(psum, 1);
            psum += __shfl_xor(psum, 2);
            psum += __shfl_xor(psum, 4);
            psum += __shfl_xor(psum, 8);
            l_run[j] = l_run[j] * resc + psum;
            m_run[j] = m_new;
            acc_o[0][j] *= resc; acc_o[1][j] *= resc;
            acc_o[2][j] *= resc; acc_o[3][j] *= resc;
        }

        asm volatile("s_waitcnt lgkmcnt(0)" ::: "memory");

        bh8 ap0 = *(const bh8*)&Pl[w * 16 + l15][     g * 8];
        bh8 ap1 = *(const bh8*)&Pl[w * 16 + l15][32 + g * 8];
        #pragma unroll
        for (int c2 = 0; c2 < 4; ++c2) {
            bh8 bv0 = *(const bh8*)&Vl[c2 * 16 + l15][     g * 8];
            bh8 bv1 = *(const bh8*)&Vl[c2 * 16 + l15][32 + g * 8];
            acc_o[c2] = __builtin_amdgcn_mfma_f32_16x16x32_bf16(ap0, bv0, acc_o[c2], 0, 0, 0);
            acc_o[c2] = __builtin_amdgcn_mfma_f32_16x16x32_bf16(ap1, bv1, acc_o[c2], 0, 0, 0);
        }
    }

    #pragma unroll
    for (int j = 0; j < 4; ++j) {
        float linv = 1.f / l_run[j];
        #pragma unroll
        for (int c2 = 0; c2 < 4; ++c2)
            outb[((size_t)(b * S_ + qd + j)) * D_ + h * DK_ + c2 * 16 + l15] =
                f2bf(acc_o[c2][j] * linv);
    }
}

extern "C" void kernel_launch(void* const* d_in, const int* in_sizes, int n_in,
                              void* d_out, int out_size, void* d_ws, size_t ws_size,
                              hipStream_t stream)
{
    const float* x     = (const float*)d_in[0];
    const int*   pm    = (const int*)  d_in[1];
    const float* tm    = (const float*)d_in[2];
    const float* wq    = (const float*)d_in[3];
    const float* bq    = (const float*)d_in[4];
    const float* wk    = (const float*)d_in[5];
    const float* bk    = (const float*)d_in[6];
    const float* wv    = (const float*)d_in[7];
    const float* bv    = (const float*)d_in[8];
    const float* wp    = (const float*)d_in[9];
    const float* bp    = (const float*)d_in[10];
    const float* w_tb1 = (const float*)d_in[11];
    const float* b_tb1 = (const float*)d_in[12];
    const float* w_tb2 = (const float*)d_in[13];
    const float* b_tb2 = (const float*)d_in[14];

    char* wsb = (char*)d_ws;
    const size_t MB = 1u << 20;
    unsigned short* xb   = (unsigned short*)wsb;              // 8MB; reused as attn out
    unsigned short* wqkv = (unsigned short*)(wsb + 8  * MB);  // 6MB (3072x1024 bf16)
    unsigned short* wtp  = (unsigned short*)(wsb + 14 * MB);  // 2MB
    unsigned short* qw   = (unsigned short*)(wsb + 16 * MB);  // 8MB (B,H,S,DK)
    unsigned short* kw   = (unsigned short*)(wsb + 24 * MB);  // 8MB (B,H,S,DK)
    unsigned short* vtw  = (unsigned short*)(wsb + 32 * MB);  // 8MB (B,H,DK,S)
    unsigned short* bw   = (unsigned short*)(wsb + 40 * MB);  // 4MB bf16 (B,S,S)

    cvt_x_kernel<<<2048, 256, 0, stream>>>(x, xb, 524288);
    dim3 gw(16, 16, 4);
    cvt_wt4_kernel<<<gw, 256, 0, stream>>>(wq, wk, wv, wp,
                                           wqkv, wqkv + 1048576, wqkv + 2097152, wtp);

    dim3 gqkv(32, 48);
    gemm_qkv_kernel<<<gqkv, 256, 0, stream>>>(xb, wqkv, bq, bk, bv, qw, kw, vtw);

    tbias_kernel<<<2048, 256, 0, stream>>>(tm, pm, w_tb1, b_tb1, w_tb2, b_tb2, bw);

    attn_kernel<<<1024, 256, 0, stream>>>(qw, kw, vtw, bw, xb /*out*/);

    dim3 gp(64, 16);
    gemm_proj_kernel<<<gp, 256, 0, stream>>>(xb, wtp, bp, (float*)d_out);
}